// Round 12
// baseline (341.013 us; speedup 1.0000x reference)
//
#include <hip/hip_runtime.h>
#include <hip/hip_bf16.h>

// B=128, N=50, NB=32, K=8, H=64, D=512. sites=6400, neighbor rows=204800.
// Fused: per block, 64 neighbor rows (=2 sites) GEMM (bf16 MFMA) into LDS zbuf
// (bf16), then 3 routing iterations in-block, write fp32 out.
// This round: B fragments load DIRECTLY global->VGPR (wave-private, perfectly
// 64B-coalesced, L2-resident) — no B LDS staging, no B barriers. Only A goes
// through LDS (shared x4 waves), single-type DMA ledger vmcnt(2).

#define D_DIM 512
#define BM 64
#define BK 32
#define KSTEPS 16

typedef __attribute__((ext_vector_type(8))) short short8;
typedef __attribute__((ext_vector_type(4))) short short4v;
typedef __attribute__((ext_vector_type(4))) float f32x4;

static __device__ __forceinline__ short f2bf(float f) {
    __bf16 b = (__bf16)f;
    return __builtin_bit_cast(short, b);
}
static __device__ __forceinline__ float bf2f(short s) {
    unsigned u = ((unsigned)(unsigned short)s) << 16;
    return __builtin_bit_cast(float, u);
}
static __device__ __forceinline__ void gload_lds16(const void* g, void* l) {
    __builtin_amdgcn_global_load_lds(
        (const __attribute__((address_space(1))) void*)g,
        (__attribute__((address_space(3))) void*)l, 16, 0, 0);
}

__global__ __launch_bounds__(256) void wconv(const float* __restrict__ W,
                                             short* __restrict__ Wb) {
    const int i = (blockIdx.x * 256 + threadIdx.x) * 8;
    const float4 v0 = *reinterpret_cast<const float4*>(W + i);
    const float4 v1 = *reinterpret_cast<const float4*>(W + i + 4);
    short8 o;
    o[0] = f2bf(v0.x); o[1] = f2bf(v0.y); o[2] = f2bf(v0.z); o[3] = f2bf(v0.w);
    o[4] = f2bf(v1.x); o[5] = f2bf(v1.y); o[6] = f2bf(v1.z); o[7] = f2bf(v1.w);
    *reinterpret_cast<short8*>(Wb + i) = o;
}

// 256 threads = 4 waves; wave w -> 64 rows x cols [128w,128w+128).
// lAf32[2]: [64][32] f32 (8 KB each) via DMA; row = 8 x 16B slots,
//   phys slot P = (G + row) & 7; 2 DMAs/wave/step.
// B: per-wave direct loads; frag n: lane reads Wb[(wc+n*16+l15)*512 + k0 + q*8].
template <bool FUSED>
__global__ __launch_bounds__(256, 2) void gemm_route(
    const float* __restrict__ A,     // [R,512] fp32
    const short* __restrict__ Wb,    // [512,512] bf16
    const float* __restrict__ bias,  // [512]
    short* __restrict__ Zs,          // !FUSED: s output bf16
    const short* __restrict__ S,     // FUSED: s input bf16
    const int* __restrict__ miter_ptr,
    float* __restrict__ out)         // FUSED: [sites,512] fp32
{
    __shared__ __align__(16) char smem[81920];
    float* const lAf32 = (float*)smem;            // [2][2048] f32 (16 KB)
    short* const zbuf = (short*)(smem + 16384);   // [64][512] bf16 (64 KB)

    const int t = threadIdx.x;
    const int lane = t & 63;
    const int wid = t >> 6;
    const size_t row0 = (size_t)blockIdx.x * BM;
    const int wc = wid * 128;
    const int l15 = lane & 15;
    const int q = lane >> 4;

    const int cb = wc + l15;
    float bcol[8];
    #pragma unroll
    for (int n = 0; n < 8; ++n) bcol[n] = bias[cb + n * 16];
    int miter = 0;
    if (FUSED) miter = *miter_ptr;

    // A staging: 2 DMAs/wave/step (chunk = 8 rows x 128 B), full-rotation swizzle.
    auto stageA = [&](int step, int buf) {
        const int k0 = step * BK;
        #pragma unroll
        for (int i = 0; i < 2; ++i) {
            const int c = wid * 2 + i;
            const int r = c * 8 + (lane >> 3);
            const int g = ((lane & 7) - (lane >> 3)) & 7;
            gload_lds16(A + (row0 + r) * D_DIM + k0 + g * 4,
                        lAf32 + buf * 2048 + c * 256);
        }
    };

    // B fragment base: row (wc + n*16 + l15), k-bytes 2*k0 + q*16.
    const short* const bBase = Wb + (size_t)(wc + l15) * D_DIM + q * 8;

    f32x4 acc[4][8] = {};
    auto compute = [&](int buf, int k0) {
        short8 bfr[8];
        #pragma unroll
        for (int n = 0; n < 8; ++n)
            bfr[n] = *reinterpret_cast<const short8*>(
                bBase + (size_t)n * 16 * D_DIM + k0);
        short8 af[4];
        #pragma unroll
        for (int m = 0; m < 4; ++m) {
            const int r = m * 16 + l15;
            const float* rowp = lAf32 + buf * 2048 + r * 32;
            const int P0 = (2 * q + r) & 7;
            const int P1 = (2 * q + 1 + r) & 7;
            const f32x4 a0 = *reinterpret_cast<const f32x4*>(rowp + P0 * 4);
            const f32x4 a1 = *reinterpret_cast<const f32x4*>(rowp + P1 * 4);
            short8 f;
            f[0] = f2bf(a0[0]); f[1] = f2bf(a0[1]);
            f[2] = f2bf(a0[2]); f[3] = f2bf(a0[3]);
            f[4] = f2bf(a1[0]); f[5] = f2bf(a1[1]);
            f[6] = f2bf(a1[2]); f[7] = f2bf(a1[3]);
            af[m] = f;
        }
        #pragma unroll
        for (int m = 0; m < 4; ++m)
            #pragma unroll
            for (int n = 0; n < 8; ++n)
                acc[m][n] = __builtin_amdgcn_mfma_f32_16x16x32_bf16(
                    af[m], bfr[n], acc[m][n], 0, 0, 0);
    };

    // ---- pipeline: A-only DMA ledger. vmcnt(2) leaves the newest stage flying.
    stageA(0, 0);
    stageA(1, 1);
    asm volatile("s_waitcnt vmcnt(2)" ::: "memory");   // A0 (+scalars) done
    __builtin_amdgcn_s_barrier();
    #pragma unroll
    for (int tk = 0; tk < KSTEPS - 2; ++tk) {          // tk = 0..13
        compute(tk & 1, tk * BK);
        asm volatile("s_waitcnt lgkmcnt(0)" ::: "memory");  // lA reads consumed
        __builtin_amdgcn_s_barrier();                       // buf tk&1 free
        stageA(tk + 2, tk & 1);                             // overwrite it
        __builtin_amdgcn_sched_barrier(0);                  // pin wait to stage
        asm volatile("s_waitcnt vmcnt(2)" ::: "memory");    // A(tk+1) retired
        __builtin_amdgcn_s_barrier();                       // visible to all
    }
    // tk = 14: drain A(15) (issued at tk=13 — full-step cover)
    compute(0, 14 * BK);
    asm volatile("s_waitcnt lgkmcnt(0)" ::: "memory");
    __builtin_amdgcn_s_barrier();
    asm volatile("s_waitcnt vmcnt(0)" ::: "memory");
    __builtin_amdgcn_s_barrier();
    // tk = 15
    compute(1, 15 * BK);

    // ---- epilogue: bias + ReLU + l2norm per 64-col group; z as bf16.
    // (zbuf is its own LDS region — no barrier needed before writing it.)
    #pragma unroll
    for (int m = 0; m < 4; ++m) {
        #pragma unroll
        for (int r = 0; r < 4; ++r) {
            float v[8];
            float ssa = 0.0f, ssb = 0.0f;
            #pragma unroll
            for (int n = 0; n < 4; ++n) {
                v[n] = fmaxf(acc[m][n][r] + bcol[n], 0.0f);
                ssa = fmaf(v[n], v[n], ssa);
            }
            #pragma unroll
            for (int n = 4; n < 8; ++n) {
                v[n] = fmaxf(acc[m][n][r] + bcol[n], 0.0f);
                ssb = fmaf(v[n], v[n], ssb);
            }
            ssa += __shfl_xor(ssa, 1); ssb += __shfl_xor(ssb, 1);
            ssa += __shfl_xor(ssa, 2); ssb += __shfl_xor(ssb, 2);
            ssa += __shfl_xor(ssa, 4); ssb += __shfl_xor(ssb, 4);
            ssa += __shfl_xor(ssa, 8); ssb += __shfl_xor(ssb, 8);
            const float inva = 1.0f / fmaxf(sqrtf(ssa), 1e-12f);
            const float invb = 1.0f / fmaxf(sqrtf(ssb), 1e-12f);
            const int orow = m * 16 + q * 4 + r;   // 0..63
            if (FUSED) {
                #pragma unroll
                for (int n = 0; n < 4; ++n)
                    zbuf[orow * D_DIM + cb + n * 16] = f2bf(v[n] * inva);
                #pragma unroll
                for (int n = 4; n < 8; ++n)
                    zbuf[orow * D_DIM + cb + n * 16] = f2bf(v[n] * invb);
            } else {
                #pragma unroll
                for (int n = 0; n < 4; ++n)
                    Zs[(row0 + orow) * D_DIM + cb + n * 16] = f2bf(v[n] * inva);
                #pragma unroll
                for (int n = 4; n < 8; ++n)
                    Zs[(row0 + orow) * D_DIM + cb + n * 16] = f2bf(v[n] * invb);
            }
        }
    }

    if (!FUSED) return;
    __syncthreads();   // zbuf complete; lA free for routing scratch

    // ---- routing (verified): 2 sites/block, 128 threads each.
    float* const scratch = (float*)smem;          // aliases lAf32
    const int tt = t & 127;
    const int ssid = t >> 7;
    const size_t site = (size_t)blockIdx.x * 2 + ssid;
    float* const u_ = scratch + ssid * 512;                 // [0, 4096)
    float* const p_ = (float*)(smem + 4096) + ssid * 256;   // [4096, 6144)
    const short* const zr = zbuf + ssid * 32 * D_DIM;

    const int e = tt * 4;
    const int go = tt >> 4;
    const short4v sv = *reinterpret_cast<const short4v*>(S + site * D_DIM + e);
    const float s0 = bf2f(sv[0]), s1 = bf2f(sv[1]);
    const float s2 = bf2f(sv[2]), s3 = bf2f(sv[3]);

    float v0, v1, v2, v3;
    {   // iteration 0: p uniform 1/8
        float a0 = 0, a1 = 0, a2 = 0, a3 = 0;
        for (int m = 0; m < 32; ++m) {
            const short4v z = *reinterpret_cast<const short4v*>(zr + m * D_DIM + e);
            a0 += bf2f(z[0]); a1 += bf2f(z[1]); a2 += bf2f(z[2]); a3 += bf2f(z[3]);
        }
        v0 = fmaf(a0, 0.125f, s0); v1 = fmaf(a1, 0.125f, s1);
        v2 = fmaf(a2, 0.125f, s2); v3 = fmaf(a3, 0.125f, s3);
    }

    const int dm = tt >> 2;
    const int ka = (tt & 3) * 2;

    for (int it = 1; it < miter; ++it) {
        float ssum = v0 * v0 + v1 * v1 + v2 * v2 + v3 * v3;
        ssum += __shfl_xor(ssum, 1);
        ssum += __shfl_xor(ssum, 2);
        ssum += __shfl_xor(ssum, 4);
        ssum += __shfl_xor(ssum, 8);
        const float inv = 1.0f / fmaxf(sqrtf(ssum), 1e-12f);
        v0 *= inv; v1 *= inv; v2 *= inv; v3 *= inv;
        *reinterpret_cast<float4*>(u_ + e) = make_float4(v0, v1, v2, v3);
        __syncthreads();

        const short* const za = zr + dm * D_DIM + ka * 64;
        const float* const ua = u_ + ka * 64;
        float da = 0, db = 0;
        #pragma unroll
        for (int j = 0; j < 8; ++j) {
            const int jj = ((j + (tt & 7)) & 7) * 8;
            const short8 zva = *reinterpret_cast<const short8*>(za + jj);
            const short8 zvb = *reinterpret_cast<const short8*>(za + 64 + jj);
            const f32x4 uA0 = *reinterpret_cast<const f32x4*>(ua + jj);
            const f32x4 uA1 = *reinterpret_cast<const f32x4*>(ua + jj + 4);
            const f32x4 uB0 = *reinterpret_cast<const f32x4*>(ua + 64 + jj);
            const f32x4 uB1 = *reinterpret_cast<const f32x4*>(ua + 64 + jj + 4);
            #pragma unroll
            for (int qq = 0; qq < 4; ++qq) {
                da = fmaf(bf2f(zva[qq]), uA0[qq], da);
                da = fmaf(bf2f(zva[qq + 4]), uA1[qq], da);
                db = fmaf(bf2f(zvb[qq]), uB0[qq], db);
                db = fmaf(bf2f(zvb[qq + 4]), uB1[qq], db);
            }
        }
        float mx = fmaxf(da, db);
        mx = fmaxf(mx, __shfl_xor(mx, 1));
        mx = fmaxf(mx, __shfl_xor(mx, 2));
        const float ea = __expf(da - mx), eb = __expf(db - mx);
        float sm_ = ea + eb;
        sm_ += __shfl_xor(sm_, 1);
        sm_ += __shfl_xor(sm_, 2);
        const float rs = 1.0f / sm_;
        *reinterpret_cast<float2*>(p_ + dm * 8 + ka) = make_float2(ea * rs, eb * rs);
        __syncthreads();

        float a0 = 0, a1 = 0, a2 = 0, a3 = 0;
        for (int m = 0; m < 32; ++m) {
            const short4v z = *reinterpret_cast<const short4v*>(zr + m * D_DIM + e);
            const float pm = p_[m * 8 + go];
            a0 = fmaf(bf2f(z[0]), pm, a0); a1 = fmaf(bf2f(z[1]), pm, a1);
            a2 = fmaf(bf2f(z[2]), pm, a2); a3 = fmaf(bf2f(z[3]), pm, a3);
        }
        v0 = s0 + a0; v1 = s1 + a1; v2 = s2 + a2; v3 = s3 + a3;
    }

    *reinterpret_cast<float4*>(out + site * D_DIM + e) =
        make_float4(fmaxf(v0, 0.0f), fmaxf(v1, 0.0f),
                    fmaxf(v2, 0.0f), fmaxf(v3, 0.0f));
}

extern "C" void kernel_launch(void* const* d_in, const int* in_sizes, int n_in,
                              void* d_out, int out_size, void* d_ws, size_t ws_size,
                              hipStream_t stream) {
    const float* self_v  = (const float*)d_in[0];   // [6400,512]
    const float* neigh_v = (const float*)d_in[1];   // [204800,512]
    const float* W1      = (const float*)d_in[2];   // [512,512]
    const float* b1      = (const float*)d_in[3];   // [512]
    const int*   miter   = (const int*)d_in[4];
    float* out = (float*)d_out;

    const int sites = in_sizes[0] / D_DIM;          // 6400
    const int nrows = in_sizes[1] / D_DIM;          // 204800

    short* s  = (short*)d_ws;                       // [sites,512] bf16
    short* Wb = s + (size_t)sites * D_DIM;          // [512,512] bf16

    wconv<<<dim3(D_DIM * D_DIM / (256 * 8)), dim3(256), 0, stream>>>(W1, Wb);
    gemm_route<false><<<dim3(sites / BM), dim3(256), 0, stream>>>(
        self_v, Wb, b1, s, nullptr, nullptr, nullptr);
    gemm_route<true><<<dim3(nrows / BM), dim3(256), 0, stream>>>(
        neigh_v, Wb, b1, nullptr, s, miter, out);
}

// Round 14
// 327.063 us; speedup vs baseline: 1.0427x; 1.0427x over previous
//
#include <hip/hip_runtime.h>
#include <hip/hip_bf16.h>

// B=128, N=50, NB=32, K=8, H=64, D=512. sites=6400, neighbor rows=204800.
// Fused: per block, 32 neighbor rows (=1 site) GEMM (bf16 MFMA) into LDS zbuf
// (bf16), then routing in-block, write fp32 out.
// Occupancy play: LDS = lA 8K + lB 32K single-buffered (zbuf aliases lB)
// = 40 KB -> 3 blocks/CU. Single-buf B's per-step latency covered by
// cross-block TLP. Ledger: per step issue B(tk)x8 THEN A(tk+1)x1 (order
// PINNED by sched_barrier(0) — the race fix vs round 13), s_waitcnt vmcnt(1)
// retires A(tk)+B(tk)x8, leaves A(tk+1) in flight.

#define D_DIM 512
#define BM 32
#define BK 32
#define KSTEPS 16

typedef __attribute__((ext_vector_type(8))) short short8;
typedef __attribute__((ext_vector_type(4))) short short4v;
typedef __attribute__((ext_vector_type(4))) float f32x4;

static __device__ __forceinline__ short f2bf(float f) {
    __bf16 b = (__bf16)f;
    return __builtin_bit_cast(short, b);
}
static __device__ __forceinline__ float bf2f(short s) {
    unsigned u = ((unsigned)(unsigned short)s) << 16;
    return __builtin_bit_cast(float, u);
}
static __device__ __forceinline__ void gload_lds16(const void* g, void* l) {
    __builtin_amdgcn_global_load_lds(
        (const __attribute__((address_space(1))) void*)g,
        (__attribute__((address_space(3))) void*)l, 16, 0, 0);
}

__global__ __launch_bounds__(256) void wconv(const float* __restrict__ W,
                                             short* __restrict__ Wb) {
    const int i = (blockIdx.x * 256 + threadIdx.x) * 8;
    const float4 v0 = *reinterpret_cast<const float4*>(W + i);
    const float4 v1 = *reinterpret_cast<const float4*>(W + i + 4);
    short8 o;
    o[0] = f2bf(v0.x); o[1] = f2bf(v0.y); o[2] = f2bf(v0.z); o[3] = f2bf(v0.w);
    o[4] = f2bf(v1.x); o[5] = f2bf(v1.y); o[6] = f2bf(v1.z); o[7] = f2bf(v1.w);
    *reinterpret_cast<short8*>(Wb + i) = o;
}

// 256 threads = 4 waves; wave w -> 32 rows x cols [128w,128w+128).
template <bool FUSED>
__global__ __launch_bounds__(256, 3) void gemm_route(
    const float* __restrict__ A,     // [R,512] fp32
    const short* __restrict__ Wb,    // [512,512] bf16
    const float* __restrict__ bias,  // [512]
    short* __restrict__ Zs,          // !FUSED: s output bf16
    const short* __restrict__ S,     // FUSED: s input bf16
    const int* __restrict__ miter_ptr,
    float* __restrict__ out)         // FUSED: [sites,512] fp32
{
    __shared__ __align__(16) char smem[40960];
    float* const lAf32 = (float*)smem;           // [2][1024] f32 (8 KB)
    short* const lB = (short*)(smem + 8192);     // [512][32] bf16 (32 KB)

    const int t = threadIdx.x;
    const int lane = t & 63;
    const int wid = t >> 6;
    const size_t row0 = (size_t)blockIdx.x * BM;
    const int wc = wid * 128;
    const int l15 = lane & 15;
    const int q = lane >> 4;

    const int cb = wc + l15;
    float bcol[8];
    #pragma unroll
    for (int n = 0; n < 8; ++n) bcol[n] = bias[cb + n * 16];
    int miter = 0;
    if (FUSED) miter = *miter_ptr;

    // B: 32 chunks of 1024 B (16 rows x 64 B); wave w -> chunks [8w, 8w+8).
    auto stageB = [&](int step) {
        const int k0 = step * BK;
        #pragma unroll
        for (int i = 0; i < 8; ++i) {
            const int c = wid * 8 + i;
            const int r = c * 16 + (lane >> 2);
            const int g = ((lane & 3) - (r >> 1)) & 3;
            gload_lds16(Wb + (size_t)r * D_DIM + k0 + g * 8, lB + c * 512);
        }
    };
    // A: 4 chunks of 1024 B (8 rows x 128 B); wave w -> chunk w. 1 DMA/wave.
    auto stageA = [&](int step, int buf) {
        const int k0 = (step < KSTEPS ? step : 0) * BK;
        const int r = wid * 8 + (lane >> 3);
        const int g = ((lane & 7) - (lane >> 3)) & 7;
        gload_lds16(A + (row0 + r) * D_DIM + k0 + g * 4,
                    lAf32 + buf * 1024 + wid * 256);
    };

    f32x4 acc[2][8] = {};
    auto compute = [&](int buf) {
        short8 af[2], bfr[8];
        #pragma unroll
        for (int m = 0; m < 2; ++m) {
            const int r = m * 16 + l15;
            const float* rowp = lAf32 + buf * 1024 + r * 32;
            const int P0 = (2 * q + r) & 7;
            const int P1 = (2 * q + 1 + r) & 7;
            const f32x4 a0 = *reinterpret_cast<const f32x4*>(rowp + P0 * 4);
            const f32x4 a1 = *reinterpret_cast<const f32x4*>(rowp + P1 * 4);
            short8 f;
            f[0] = f2bf(a0[0]); f[1] = f2bf(a0[1]);
            f[2] = f2bf(a0[2]); f[3] = f2bf(a0[3]);
            f[4] = f2bf(a1[0]); f[5] = f2bf(a1[1]);
            f[6] = f2bf(a1[2]); f[7] = f2bf(a1[3]);
            af[m] = f;
        }
        #pragma unroll
        for (int n = 0; n < 8; ++n) {
            const int r = wc + n * 16 + l15;
            bfr[n] = *reinterpret_cast<const short8*>(
                lB + r * 32 + ((q + (r >> 1)) & 3) * 8);
        }
        #pragma unroll
        for (int m = 0; m < 2; ++m)
            #pragma unroll
            for (int n = 0; n < 8; ++n)
                acc[m][n] = __builtin_amdgcn_mfma_f32_16x16x32_bf16(
                    af[m], bfr[n], acc[m][n], 0, 0, 0);
    };

    // ---- pipeline: single-buf B, A 2-deep; issue order PINNED (race fix).
    stageA(0, 0);
    #pragma unroll
    for (int tk = 0; tk < KSTEPS; ++tk) {
        __builtin_amdgcn_s_barrier();           // lB free (all read prev step)
        __builtin_amdgcn_sched_barrier(0);      // nothing hoists above barrier
        stageB(tk);
        __builtin_amdgcn_sched_barrier(0);      // B(tk)x8 issue BEFORE A(tk+1)
        stageA(tk + 1, (tk + 1) & 1);           // clamped junk at tk=15
        __builtin_amdgcn_sched_barrier(0);      // pin wait after both stages
        asm volatile("s_waitcnt vmcnt(1)" ::: "memory");  // A(tk)+B(tk) done
        __builtin_amdgcn_s_barrier();           // visible to all waves
        compute(tk & 1);
    }
    asm volatile("s_waitcnt vmcnt(0)" ::: "memory");      // drain junk A(16)
    __builtin_amdgcn_s_barrier();               // all compute(15) reads done

    // ---- epilogue: bias + ReLU + l2norm per 64-col group; z as bf16.
    short* const zbuf = (short*)(smem + 8192);  // aliases lB (free now)
    #pragma unroll
    for (int m = 0; m < 2; ++m) {
        #pragma unroll
        for (int r = 0; r < 4; ++r) {
            float v[8];
            float ssa = 0.0f, ssb = 0.0f;
            #pragma unroll
            for (int n = 0; n < 4; ++n) {
                v[n] = fmaxf(acc[m][n][r] + bcol[n], 0.0f);
                ssa = fmaf(v[n], v[n], ssa);
            }
            #pragma unroll
            for (int n = 4; n < 8; ++n) {
                v[n] = fmaxf(acc[m][n][r] + bcol[n], 0.0f);
                ssb = fmaf(v[n], v[n], ssb);
            }
            ssa += __shfl_xor(ssa, 1); ssb += __shfl_xor(ssb, 1);
            ssa += __shfl_xor(ssa, 2); ssb += __shfl_xor(ssb, 2);
            ssa += __shfl_xor(ssa, 4); ssb += __shfl_xor(ssb, 4);
            ssa += __shfl_xor(ssa, 8); ssb += __shfl_xor(ssb, 8);
            const float inva = 1.0f / fmaxf(sqrtf(ssa), 1e-12f);
            const float invb = 1.0f / fmaxf(sqrtf(ssb), 1e-12f);
            const int orow = m * 16 + q * 4 + r;   // 0..31
            if (FUSED) {
                #pragma unroll
                for (int n = 0; n < 4; ++n)
                    zbuf[orow * D_DIM + cb + n * 16] = f2bf(v[n] * inva);
                #pragma unroll
                for (int n = 4; n < 8; ++n)
                    zbuf[orow * D_DIM + cb + n * 16] = f2bf(v[n] * invb);
            } else {
                #pragma unroll
                for (int n = 0; n < 4; ++n)
                    Zs[(row0 + orow) * D_DIM + cb + n * 16] = f2bf(v[n] * inva);
                #pragma unroll
                for (int n = 4; n < 8; ++n)
                    Zs[(row0 + orow) * D_DIM + cb + n * 16] = f2bf(v[n] * invb);
            }
        }
    }

    if (!FUSED) return;
    __syncthreads();   // zbuf complete

    // ---- routing (verified r8 code): 1 site/block; 256 threads duplicate the
    // 128-thread pattern (identical values to identical addresses — benign).
    const int tt = t & 127;
    const size_t site = (size_t)blockIdx.x;
    float* const u_ = (float*)smem;                    // 2 KB, aliases lAf32
    float* const p_ = (float*)(smem + 2048);           // 1 KB
    const short* const zr = zbuf;

    const int e = tt * 4;
    const int go = tt >> 4;                  // capsule group of owned elems
    const short4v sv = *reinterpret_cast<const short4v*>(S + site * D_DIM + e);
    const float s0 = bf2f(sv[0]), s1 = bf2f(sv[1]);
    const float s2 = bf2f(sv[2]), s3 = bf2f(sv[3]);

    float v0, v1, v2, v3;
    {   // iteration 0: p uniform 1/8
        float a0 = 0, a1 = 0, a2 = 0, a3 = 0;
        for (int m = 0; m < 32; ++m) {
            const short4v z = *reinterpret_cast<const short4v*>(zr + m * D_DIM + e);
            a0 += bf2f(z[0]); a1 += bf2f(z[1]); a2 += bf2f(z[2]); a3 += bf2f(z[3]);
        }
        v0 = fmaf(a0, 0.125f, s0); v1 = fmaf(a1, 0.125f, s1);
        v2 = fmaf(a2, 0.125f, s2); v3 = fmaf(a3, 0.125f, s3);
    }

    const int dm = tt >> 2;                  // neighbor for this thread's dots
    const int ka = (tt & 3) * 2;             // capsule pair

    for (int it = 1; it < miter; ++it) {
        // normalize u per 64-group (16-thread shfl groups, wave-aligned)
        float ssum = v0 * v0 + v1 * v1 + v2 * v2 + v3 * v3;
        ssum += __shfl_xor(ssum, 1);
        ssum += __shfl_xor(ssum, 2);
        ssum += __shfl_xor(ssum, 4);
        ssum += __shfl_xor(ssum, 8);
        const float inv = 1.0f / fmaxf(sqrtf(ssum), 1e-12f);
        v0 *= inv; v1 *= inv; v2 *= inv; v3 *= inv;
        *reinterpret_cast<float4*>(u_ + e) = make_float4(v0, v1, v2, v3);
        __syncthreads();

        // dots: p[dm][ka], p[dm][ka+1]; staggered octet reads
        const short* const za = zr + dm * D_DIM + ka * 64;
        const float* const ua = u_ + ka * 64;
        float da = 0, db = 0;
        #pragma unroll
        for (int j = 0; j < 8; ++j) {
            const int jj = ((j + (tt & 7)) & 7) * 8;
            const short8 zva = *reinterpret_cast<const short8*>(za + jj);
            const short8 zvb = *reinterpret_cast<const short8*>(za + 64 + jj);
            const f32x4 uA0 = *reinterpret_cast<const f32x4*>(ua + jj);
            const f32x4 uA1 = *reinterpret_cast<const f32x4*>(ua + jj + 4);
            const f32x4 uB0 = *reinterpret_cast<const f32x4*>(ua + 64 + jj);
            const f32x4 uB1 = *reinterpret_cast<const f32x4*>(ua + 64 + jj + 4);
            #pragma unroll
            for (int qq = 0; qq < 4; ++qq) {
                da = fmaf(bf2f(zva[qq]), uA0[qq], da);
                da = fmaf(bf2f(zva[qq + 4]), uA1[qq], da);
                db = fmaf(bf2f(zvb[qq]), uB0[qq], db);
                db = fmaf(bf2f(zvb[qq + 4]), uB1[qq], db);
            }
        }
        // softmax over 8 k (4 threads x 2 vals)
        float mx = fmaxf(da, db);
        mx = fmaxf(mx, __shfl_xor(mx, 1));
        mx = fmaxf(mx, __shfl_xor(mx, 2));
        const float ea = __expf(da - mx), eb = __expf(db - mx);
        float sm_ = ea + eb;
        sm_ += __shfl_xor(sm_, 1);
        sm_ += __shfl_xor(sm_, 2);
        const float rs = 1.0f / sm_;
        *reinterpret_cast<float2*>(p_ + dm * 8 + ka) = make_float2(ea * rs, eb * rs);
        __syncthreads();

        // u = s + sum_m z[m]*p[m, go]
        float a0 = 0, a1 = 0, a2 = 0, a3 = 0;
        for (int m = 0; m < 32; ++m) {
            const short4v z = *reinterpret_cast<const short4v*>(zr + m * D_DIM + e);
            const float pm = p_[m * 8 + go];
            a0 = fmaf(bf2f(z[0]), pm, a0); a1 = fmaf(bf2f(z[1]), pm, a1);
            a2 = fmaf(bf2f(z[2]), pm, a2); a3 = fmaf(bf2f(z[3]), pm, a3);
        }
        v0 = s0 + a0; v1 = s1 + a1; v2 = s2 + a2; v3 = s3 + a3;
        // next p_ write is after next norm's barrier -> safe
    }

    *reinterpret_cast<float4*>(out + site * D_DIM + e) =
        make_float4(fmaxf(v0, 0.0f), fmaxf(v1, 0.0f),
                    fmaxf(v2, 0.0f), fmaxf(v3, 0.0f));
}

extern "C" void kernel_launch(void* const* d_in, const int* in_sizes, int n_in,
                              void* d_out, int out_size, void* d_ws, size_t ws_size,
                              hipStream_t stream) {
    const float* self_v  = (const float*)d_in[0];   // [6400,512]
    const float* neigh_v = (const float*)d_in[1];   // [204800,512]
    const float* W1      = (const float*)d_in[2];   // [512,512]
    const float* b1      = (const float*)d_in[3];   // [512]
    const int*   miter   = (const int*)d_in[4];
    float* out = (float*)d_out;

    const int sites = in_sizes[0] / D_DIM;          // 6400
    const int nrows = in_sizes[1] / D_DIM;          // 204800

    short* s  = (short*)d_ws;                       // [sites,512] bf16
    short* Wb = s + (size_t)sites * D_DIM;          // [512,512] bf16

    wconv<<<dim3(D_DIM * D_DIM / (256 * 8)), dim3(256), 0, stream>>>(W1, Wb);
    gemm_route<false><<<dim3(sites / BM), dim3(256), 0, stream>>>(
        self_v, Wb, b1, s, nullptr, nullptr, nullptr);
    gemm_route<true><<<dim3(nrows / BM), dim3(256), 0, stream>>>(
        neigh_v, Wb, b1, nullptr, s, miter, out);
}